// Round 4
// baseline (322.751 us; speedup 1.0000x reference)
//
#include <hip/hip_runtime.h>

#define N_NODES 100000
#define N_EDGES 1600000
#define MPAD    100096   /* 782 * 128 */
#define MTILES  782

#define NB      391      /* ceil(100000/256) buckets of 256 nodes */
#define CH      8192     /* edges per phase-A block */
#define NBLK_A  196      /* ceil(1600000/8192) */

#define AGG_WAVES 8192   /* one full round: 256 CU x 32 waves */
#define EPW       196    /* ceil((N_EDGES+1)/AGG_WAVES) */

typedef __attribute__((ext_vector_type(8))) short short8;
typedef __attribute__((ext_vector_type(4))) float f32x4;

static __device__ __forceinline__ unsigned short f2bf(float f) {
  unsigned u = __builtin_bit_cast(unsigned, f);
  u += 0x7fffu + ((u >> 16) & 1u);     // round-to-nearest-even
  return (unsigned short)(u >> 16);
}
static __device__ __forceinline__ float bf2f(unsigned short s) {
  unsigned u = ((unsigned)s) << 16;
  return __builtin_bit_cast(float, u);
}

// ---------------- CSR build: two-level LDS counting sort ----------------

__global__ __launch_bounds__(256) void k_bhist(const int* __restrict__ row,
                                               int* __restrict__ Hc) {
  __shared__ int hist[NB];
  int b = blockIdx.x, t = threadIdx.x;
  for (int j = t; j < NB; j += 256) hist[j] = 0;
  __syncthreads();
  int base = b * CH;
  #pragma unroll
  for (int k = 0; k < 8; ++k) {
    int i = base + k * 1024 + t * 4;
    if (i < N_EDGES) {
      int4 r = *(const int4*)(row + i);
      atomicAdd(&hist[r.x >> 8], 1);
      atomicAdd(&hist[r.y >> 8], 1);
      atomicAdd(&hist[r.z >> 8], 1);
      atomicAdd(&hist[r.w >> 8], 1);
    }
  }
  __syncthreads();
  for (int j = t; j < NB; j += 256) Hc[j * NBLK_A + b] = hist[j];
}

__global__ __launch_bounds__(512) void k_bscan(const int* __restrict__ Hc,
                                               int* __restrict__ Boff) {
  int t = threadIdx.x;
  int total = 0;
  if (t < NB) {
    const int* p = Hc + t * NBLK_A;
    for (int i = 0; i < NBLK_A; i += 4) {
      int4 v = *(const int4*)(p + i);
      total += v.x + v.y + v.z + v.w;
    }
  }
  int lane = t & 63, w = t >> 6;
  int incl = total;
  #pragma unroll
  for (int off = 1; off < 64; off <<= 1) {
    int n = __shfl_up(incl, off, 64);
    if (lane >= off) incl += n;
  }
  __shared__ int ws[8];
  if (lane == 63) ws[w] = incl;
  __syncthreads();
  int wo = 0;
  for (int ww = 0; ww < w; ++ww) wo += ws[ww];
  int excl = wo + incl - total;
  if (t < NB) Boff[t] = excl;
  if (t == NB - 1) Boff[NB] = excl + total;
}

__global__ __launch_bounds__(64) void k_bexp(const int* __restrict__ Hc,
                                             const int* __restrict__ Boff,
                                             int* __restrict__ G) {
  int b = blockIdx.x, l = threadIdx.x;
  int run = Boff[b];
  const int* p = Hc + b * NBLK_A;
  for (int c = 0; c < NBLK_A; c += 64) {
    int idx = c + l;
    int v = (idx < NBLK_A) ? p[idx] : 0;
    int incl = v;
    #pragma unroll
    for (int off = 1; off < 64; off <<= 1) {
      int n = __shfl_up(incl, off, 64);
      if (l >= off) incl += n;
    }
    if (idx < NBLK_A) G[b * NBLK_A + idx] = run + incl - v;
    run += __shfl(incl, 63, 64);
  }
}

__global__ __launch_bounds__(256) void k_bscat(const int* __restrict__ row,
                                               const int* __restrict__ col,
                                               const int* __restrict__ G,
                                               unsigned* __restrict__ tmp) {
  __shared__ int cur[NB];
  int b = blockIdx.x, t = threadIdx.x;
  for (int j = t; j < NB; j += 256) cur[j] = G[j * NBLK_A + b];
  __syncthreads();
  int base = b * CH;
  #pragma unroll
  for (int k = 0; k < 8; ++k) {
    int i = base + k * 1024 + t * 4;
    if (i < N_EDGES) {
      int4 r = *(const int4*)(row + i);
      int4 c = *(const int4*)(col + i);
      int p0 = atomicAdd(&cur[r.x >> 8], 1);
      tmp[p0] = (unsigned)c.x | ((unsigned)(r.x & 255) << 24);
      int p1 = atomicAdd(&cur[r.y >> 8], 1);
      tmp[p1] = (unsigned)c.y | ((unsigned)(r.y & 255) << 24);
      int p2 = atomicAdd(&cur[r.z >> 8], 1);
      tmp[p2] = (unsigned)c.z | ((unsigned)(r.z & 255) << 24);
      int p3 = atomicAdd(&cur[r.w >> 8], 1);
      tmp[p3] = (unsigned)c.w | ((unsigned)(r.w & 255) << 24);
    }
  }
}

__global__ __launch_bounds__(256) void k_bsort(const unsigned* __restrict__ tmp,
                                               const int* __restrict__ Boff,
                                               int* __restrict__ rp,
                                               int* __restrict__ cs) {
  __shared__ int hist[256];
  __shared__ int wsum[4];
  int b = blockIdx.x, t = threadIdx.x;
  int s = Boff[b], e = Boff[b + 1];
  hist[t] = 0;
  __syncthreads();
  for (int i = s + t; i < e; i += 256) atomicAdd(&hist[tmp[i] >> 24], 1);
  __syncthreads();
  int v = hist[t];
  int lane = t & 63, w = t >> 6;
  int incl = v;
  #pragma unroll
  for (int off = 1; off < 64; off <<= 1) {
    int n = __shfl_up(incl, off, 64);
    if (lane >= off) incl += n;
  }
  if (lane == 63) wsum[w] = incl;
  __syncthreads();
  int wo = 0;
  for (int ww = 0; ww < w; ++ww) wo += wsum[ww];
  int excl = s + wo + incl - v;
  int node = (b << 8) + t;
  if (node < N_NODES) rp[node] = excl;
  __syncthreads();
  hist[t] = excl;    // reuse as cursor
  __syncthreads();
  for (int i = s + t; i < e; i += 256) {
    unsigned u = tmp[i];
    int pos = atomicAdd(&hist[u >> 24], 1);
    cs[pos] = (int)(u & 0xFFFFFFu);
  }
  if (b == 0 && t == 0) rp[N_NODES] = N_EDGES;
}

// ---------------- feature conversion / aggregation ----------------

// x f32 -> bf16 into Acat[:,128:256]
__global__ void k_cvt_x(const float* __restrict__ x, short* __restrict__ Acat) {
  int id = blockIdx.x * 256 + threadIdx.x;
  if (id >= N_NODES * 32) return;
  int node = id >> 5, c4 = id & 31;
  float4 v = *(const float4*)(x + (size_t)node * 128 + c4 * 4);
  uint2 u;
  u.x = (unsigned)f2bf(v.x) | ((unsigned)f2bf(v.y) << 16);
  u.y = (unsigned)f2bf(v.z) | ((unsigned)f2bf(v.w) << 16);
  *(uint2*)(Acat + (size_t)node * 256 + 128 + c4 * 4) = u;
}

// Edge-balanced aggregation: one wave per contiguous EPW-edge range.
// A wave owns every target t whose edge-list START rp[t] falls in
// [estart, eend); it processes that target's FULL edge list (may read past
// eend - small duplicated work, zero atomics, each row written once).
// Gathered slice = dwords [GOFF, GOFF+64) of each 256-short source row.
// RESID: add src[t, 128:256] and write f32 to dst_f32; else bf16 to dst_bf.
template <bool RESID, int GOFF>
__global__ __launch_bounds__(256) void k_agg(const int* __restrict__ rp,
                                             const int* __restrict__ cs,
                                             const short* __restrict__ src,
                                             short* __restrict__ dst_bf,
                                             float* __restrict__ dst_f32) {
  const int wid = blockIdx.x * 4 + (threadIdx.x >> 6);
  const int lane = threadIdx.x & 63;
  const int estart = wid * EPW;
  if (estart > N_EDGES) return;
  const int eend = estart + EPW;

  // lower_bound: first t in [0,N) with rp[t] >= estart
  int lo = 0, hi = N_NODES;
  while (lo < hi) {
    int mid = (lo + hi) >> 1;
    if (rp[mid] < estart) lo = mid + 1; else hi = mid;
  }
  int t = lo;

  const short* gb = src + GOFF + 2 * lane;
  while (t < N_NODES && rp[t] < eend) {
    int s = rp[t], e = rp[t + 1];
    float a0 = 0.f, a1 = 0.f;
    int i = s;
    for (; i + 8 <= e; i += 8) {
      unsigned u[8];
      #pragma unroll
      for (int q = 0; q < 8; ++q)
        u[q] = *(const unsigned*)(gb + (size_t)cs[i + q] * 256);
      #pragma unroll
      for (int q = 0; q < 8; ++q) {
        a0 += bf2f((unsigned short)u[q]);
        a1 += bf2f((unsigned short)(u[q] >> 16));
      }
    }
    for (; i < e; ++i) {
      unsigned u = *(const unsigned*)(gb + (size_t)cs[i] * 256);
      a0 += bf2f((unsigned short)u);
      a1 += bf2f((unsigned short)(u >> 16));
    }
    if (RESID) {
      unsigned r = *(const unsigned*)(src + (size_t)t * 256 + 128 + 2 * lane);
      a0 += bf2f((unsigned short)r);
      a1 += bf2f((unsigned short)(r >> 16));
      float2 o = {a0, a1};
      *(float2*)(dst_f32 + (size_t)t * 128 + 2 * lane) = o;
    } else {
      *(unsigned*)(dst_bf + (size_t)t * 256 + 2 * lane) =
          (unsigned)f2bf(a0) | ((unsigned)f2bf(a1) << 16);
    }
    ++t;
  }
}

// ---------------- GEMM ----------------

// pack B [K x GN] f32 -> bf16 MFMA-B fragment layout.
// HCAT=false: B = vstack(B0,B1)  (B0,B1 are (K/2) x GN)
// HCAT=true:  B = hstack(B0,B1)  (B0,B1 are K x (GN/2))
template <bool HCAT>
__global__ void k_pack(const float* __restrict__ B0, const float* __restrict__ B1,
                       short* __restrict__ Bp, int K, int GN) {
  int id = blockIdx.x * 256 + threadIdx.x;
  if (id >= K * GN) return;
  int j = id & 7;
  int lane = (id >> 3) & 63;
  int blk = id >> 9;
  int NBf = GN >> 4;
  int nb = blk % NBf;
  int kk = blk / NBf;
  int k = kk * 32 + (lane >> 4) * 8 + j;
  int c = nb * 16 + (lane & 15);
  float v;
  if (HCAT) {
    int half = GN >> 1;
    v = (c < half) ? B0[k * half + c] : B1[k * half + (c - half)];
  } else {
    int halfK = K >> 1;
    v = (k < halfK) ? B0[k * GN + c] : B1[(k - halfK) * GN + c];
  }
  Bp[id] = (short)f2bf(v);
}

// C[M x GN] = A[M x K](bf16) * Bp (+bias per BIAS_MODE), optional relu.
// 128x128 tile / block, 4 waves 2x2, each wave 64x64 (4x4 16x16x32 frags).
// BIAS_MODE: 0 = bias[colg]; 1 = colg<128 ? 0 : bias[colg-128]
template <int KK, int NBTOT, bool RELU, bool OUT_BF16, int BIAS_MODE>
__global__ __launch_bounds__(256) void k_gemm(const short* __restrict__ A, int lda,
                                              const short* __restrict__ Bp,
                                              const float* __restrict__ bias,
                                              void* __restrict__ out, int ldc,
                                              int col_off, int mlimit) {
  const int lane = threadIdx.x & 63;
  const int wave = threadIdx.x >> 6;
  const int wr = wave >> 1, wc = wave & 1;
  const int row0 = blockIdx.x * 128 + wr * 64;
  const int colbase = blockIdx.y * 128 + wc * 64;
  const int arow = lane & 15;
  const int kgrp = lane >> 4;

  f32x4 acc[4][4];
  const f32x4 zero = {0.f, 0.f, 0.f, 0.f};
  #pragma unroll
  for (int a = 0; a < 4; ++a)
    #pragma unroll
    for (int b = 0; b < 4; ++b) acc[a][b] = zero;

  const short* Bbase = Bp + (size_t)lane * 8;
  for (int kk = 0; kk < KK; ++kk) {
    short8 af[4], bfr[4];
    const int kb = kk * 32 + kgrp * 8;
    #pragma unroll
    for (int mi = 0; mi < 4; ++mi)
      af[mi] = *(const short8*)(A + (size_t)(row0 + mi * 16 + arow) * lda + kb);
    #pragma unroll
    for (int ni = 0; ni < 4; ++ni) {
      int nb = (colbase >> 4) + ni;
      bfr[ni] = *(const short8*)(Bbase + ((size_t)(kk * NBTOT + nb) << 9));
    }
    #pragma unroll
    for (int mi = 0; mi < 4; ++mi)
      #pragma unroll
      for (int ni = 0; ni < 4; ++ni)
        acc[mi][ni] = __builtin_amdgcn_mfma_f32_16x16x32_bf16(af[mi], bfr[ni],
                                                              acc[mi][ni], 0, 0, 0);
  }

  const int ccol = lane & 15;
  const int crow = (lane >> 4) * 4;
  #pragma unroll
  for (int ni = 0; ni < 4; ++ni) {
    const int colg = colbase + ni * 16 + ccol;
    float bv;
    if (BIAS_MODE == 0) bv = bias[colg];
    else bv = (colg < 128) ? 0.f : bias[colg - 128];
    #pragma unroll
    for (int mi = 0; mi < 4; ++mi) {
      #pragma unroll
      for (int j = 0; j < 4; ++j) {
        int rowg = row0 + mi * 16 + crow + j;
        float v = acc[mi][ni][j] + bv;
        if (RELU) v = fmaxf(v, 0.0f);
        if (OUT_BF16) {
          ((short*)out)[(size_t)rowg * ldc + col_off + colg] = (short)f2bf(v);
        } else {
          if (rowg < mlimit)
            ((float*)out)[(size_t)rowg * ldc + col_off + colg] = v;
        }
      }
    }
  }
}

extern "C" void kernel_launch(void* const* d_in, const int* in_sizes, int n_in,
                              void* d_out, int out_size, void* d_ws, size_t ws_size,
                              hipStream_t stream) {
  const float* x   = (const float*)d_in[0];
  const int*   row = (const int*)d_in[1];
  const int*   col = (const int*)d_in[2];
  const float* Wl1 = (const float*)d_in[3];
  const float* bl1 = (const float*)d_in[4];
  const float* Wr1 = (const float*)d_in[5];
  const float* Wl2 = (const float*)d_in[6];
  const float* bl2 = (const float*)d_in[7];
  const float* Wr2 = (const float*)d_in[8];
  float* out = (float*)d_out;

  char* w = (char*)d_ws;
  auto alloc = [&](size_t bytes) {
    char* p = w;
    w += (bytes + 255) & ~(size_t)255;
    return p;
  };
  short* Acat = (short*)alloc((size_t)MPAD * 256 * 2);  // [agg_x_bf16 | x_bf16]
  short* Hbuf = (short*)alloc((size_t)MPAD * 256 * 2);  // h (post-relu), bf16
  short* P    = (short*)alloc((size_t)MPAD * 256 * 2);  // [h@Wl2 | h@Wr2+bl2], bf16
  short* Bp1  = (short*)alloc(65536 * 2);               // [Wl1;Wr1] packed (vcat)
  short* Bp2  = (short*)alloc(65536 * 2);               // [Wl2|Wr2] packed (hcat)
  int* rp   = (int*)alloc((N_NODES + 1) * 4);
  int* cs   = (int*)alloc((size_t)N_EDGES * 4);
  unsigned* tmp = (unsigned*)alloc((size_t)N_EDGES * 4);
  int* Hc   = (int*)alloc((size_t)NB * NBLK_A * 4);
  int* G    = (int*)alloc((size_t)NB * NBLK_A * 4);
  int* Boff = (int*)alloc((NB + 1) * 4);

  // --- CSR build: two-level counting sort (no global data atomics) ---
  k_bhist<<<NBLK_A, 256, 0, stream>>>(row, Hc);
  k_bscan<<<1, 512, 0, stream>>>(Hc, Boff);
  k_bexp<<<NB, 64, 0, stream>>>(Hc, Boff, G);
  k_bscat<<<NBLK_A, 256, 0, stream>>>(row, col, G, tmp);
  k_bsort<<<NB, 256, 0, stream>>>(tmp, Boff, rp, cs);

  // --- weight packing + x conversion (independent of CSR) ---
  k_cvt_x<<<(N_NODES * 32 + 255) / 256, 256, 0, stream>>>(x, Acat);
  k_pack<false><<<256, 256, 0, stream>>>(Wl1, Wr1, Bp1, 256, 256);
  k_pack<true><<<256, 256, 0, stream>>>(Wl2, Wr2, Bp2, 256, 256);

  // --- layer 1: agg(x) ; h = relu([agg|x] @ [Wl1;Wr1] + bl1) -> Hbuf bf16 ---
  k_agg<false, 128><<<AGG_WAVES / 4, 256, 0, stream>>>(rp, cs, Acat, Acat, nullptr);
  k_gemm<8, 16, true, true, 0><<<dim3(MTILES, 2), 256, 0, stream>>>(
      Acat, 256, Bp1, bl1, Hbuf, 256, 0, MPAD);

  // --- layer 2: P = h @ [Wl2 | Wr2] (+bl2 on right half) ; out = agg(P_l) + P_r ---
  k_gemm<8, 16, false, true, 1><<<dim3(MTILES, 2), 256, 0, stream>>>(
      Hbuf, 256, Bp2, bl2, P, 256, 0, MPAD);
  k_agg<true, 0><<<AGG_WAVES / 4, 256, 0, stream>>>(rp, cs, P, nullptr, out);
}

// Round 5
// 322.414 us; speedup vs baseline: 1.0010x; 1.0010x over previous
//
#include <hip/hip_runtime.h>

#define N_NODES 100000
#define N_EDGES 1600000
#define MPAD    100096   /* 782 * 128 */
#define MTILES  782

#define NB      391      /* ceil(100000/256) buckets of 256 nodes */
#define CH      8192     /* edges per phase-A block */
#define NBLK_A  196      /* ceil(1600000/8192) */

typedef __attribute__((ext_vector_type(8))) short short8;
typedef __attribute__((ext_vector_type(4))) float f32x4;

static __device__ __forceinline__ unsigned short f2bf(float f) {
  unsigned u = __builtin_bit_cast(unsigned, f);
  u += 0x7fffu + ((u >> 16) & 1u);     // round-to-nearest-even
  return (unsigned short)(u >> 16);
}
static __device__ __forceinline__ float bf2f(unsigned short s) {
  unsigned u = ((unsigned)s) << 16;
  return __builtin_bit_cast(float, u);
}

// ---------------- CSR build: two-level LDS counting sort ----------------

__global__ __launch_bounds__(256) void k_bhist(const int* __restrict__ row,
                                               int* __restrict__ Hc) {
  __shared__ int hist[NB];
  int b = blockIdx.x, t = threadIdx.x;
  for (int j = t; j < NB; j += 256) hist[j] = 0;
  __syncthreads();
  int base = b * CH;
  #pragma unroll
  for (int k = 0; k < 8; ++k) {
    int i = base + k * 1024 + t * 4;
    if (i < N_EDGES) {
      int4 r = *(const int4*)(row + i);
      atomicAdd(&hist[r.x >> 8], 1);
      atomicAdd(&hist[r.y >> 8], 1);
      atomicAdd(&hist[r.z >> 8], 1);
      atomicAdd(&hist[r.w >> 8], 1);
    }
  }
  __syncthreads();
  for (int j = t; j < NB; j += 256) Hc[j * NBLK_A + b] = hist[j];
}

// also zeroes the 256-bin degree histogram (consumed later by k_dprep)
__global__ __launch_bounds__(512) void k_bscan(const int* __restrict__ Hc,
                                               int* __restrict__ Boff,
                                               int* __restrict__ Dh) {
  int t = threadIdx.x;
  if (t < 256) Dh[t] = 0;
  int total = 0;
  if (t < NB) {
    const int* p = Hc + t * NBLK_A;
    for (int i = 0; i < NBLK_A; i += 4) {
      int4 v = *(const int4*)(p + i);
      total += v.x + v.y + v.z + v.w;
    }
  }
  int lane = t & 63, w = t >> 6;
  int incl = total;
  #pragma unroll
  for (int off = 1; off < 64; off <<= 1) {
    int n = __shfl_up(incl, off, 64);
    if (lane >= off) incl += n;
  }
  __shared__ int ws[8];
  if (lane == 63) ws[w] = incl;
  __syncthreads();
  int wo = 0;
  for (int ww = 0; ww < w; ++ww) wo += ws[ww];
  int excl = wo + incl - total;
  if (t < NB) Boff[t] = excl;
  if (t == NB - 1) Boff[NB] = excl + total;
}

__global__ __launch_bounds__(64) void k_bexp(const int* __restrict__ Hc,
                                             const int* __restrict__ Boff,
                                             int* __restrict__ G) {
  int b = blockIdx.x, l = threadIdx.x;
  int run = Boff[b];
  const int* p = Hc + b * NBLK_A;
  for (int c = 0; c < NBLK_A; c += 64) {
    int idx = c + l;
    int v = (idx < NBLK_A) ? p[idx] : 0;
    int incl = v;
    #pragma unroll
    for (int off = 1; off < 64; off <<= 1) {
      int n = __shfl_up(incl, off, 64);
      if (l >= off) incl += n;
    }
    if (idx < NBLK_A) G[b * NBLK_A + idx] = run + incl - v;
    run += __shfl(incl, 63, 64);
  }
}

__global__ __launch_bounds__(256) void k_bscat(const int* __restrict__ row,
                                               const int* __restrict__ col,
                                               const int* __restrict__ G,
                                               unsigned* __restrict__ tmp) {
  __shared__ int cur[NB];
  int b = blockIdx.x, t = threadIdx.x;
  for (int j = t; j < NB; j += 256) cur[j] = G[j * NBLK_A + b];
  __syncthreads();
  int base = b * CH;
  #pragma unroll
  for (int k = 0; k < 8; ++k) {
    int i = base + k * 1024 + t * 4;
    if (i < N_EDGES) {
      int4 r = *(const int4*)(row + i);
      int4 c = *(const int4*)(col + i);
      int p0 = atomicAdd(&cur[r.x >> 8], 1);
      tmp[p0] = (unsigned)c.x | ((unsigned)(r.x & 255) << 24);
      int p1 = atomicAdd(&cur[r.y >> 8], 1);
      tmp[p1] = (unsigned)c.y | ((unsigned)(r.y & 255) << 24);
      int p2 = atomicAdd(&cur[r.z >> 8], 1);
      tmp[p2] = (unsigned)c.z | ((unsigned)(r.z & 255) << 24);
      int p3 = atomicAdd(&cur[r.w >> 8], 1);
      tmp[p3] = (unsigned)c.w | ((unsigned)(r.w & 255) << 24);
    }
  }
}

__global__ __launch_bounds__(256) void k_bsort(const unsigned* __restrict__ tmp,
                                               const int* __restrict__ Boff,
                                               int* __restrict__ rp,
                                               int* __restrict__ cs) {
  __shared__ int hist[256];
  __shared__ int wsum[4];
  int b = blockIdx.x, t = threadIdx.x;
  int s = Boff[b], e = Boff[b + 1];
  hist[t] = 0;
  __syncthreads();
  for (int i = s + t; i < e; i += 256) atomicAdd(&hist[tmp[i] >> 24], 1);
  __syncthreads();
  int v = hist[t];
  int lane = t & 63, w = t >> 6;
  int incl = v;
  #pragma unroll
  for (int off = 1; off < 64; off <<= 1) {
    int n = __shfl_up(incl, off, 64);
    if (lane >= off) incl += n;
  }
  if (lane == 63) wsum[w] = incl;
  __syncthreads();
  int wo = 0;
  for (int ww = 0; ww < w; ++ww) wo += wsum[ww];
  int excl = s + wo + incl - v;
  int node = (b << 8) + t;
  if (node < N_NODES) rp[node] = excl;
  __syncthreads();
  hist[t] = excl;    // reuse as cursor
  __syncthreads();
  for (int i = s + t; i < e; i += 256) {
    unsigned u = tmp[i];
    int pos = atomicAdd(&hist[u >> 24], 1);
    cs[pos] = (int)(u & 0xFFFFFFu);
  }
  if (b == 0 && t == 0) rp[N_NODES] = N_EDGES;
}

// ---------------- degree-sort (load balance for agg) ----------------

__global__ __launch_bounds__(256) void k_dprep(const int* __restrict__ rp,
                                               int* __restrict__ Dh) {
  __shared__ int lh[256];
  int b = blockIdx.x, t = threadIdx.x;
  lh[t] = 0;
  __syncthreads();
  int node = b * 256 + t;
  if (node < N_NODES) {
    int d = rp[node + 1] - rp[node];
    if (d > 255) d = 255;
    atomicAdd(&lh[d], 1);
  }
  __syncthreads();
  if (lh[t]) atomicAdd(&Dh[t], lh[t]);
}

__global__ __launch_bounds__(256) void k_dscan(const int* __restrict__ Dh,
                                               int* __restrict__ Dcur) {
  int t = threadIdx.x;
  int v = Dh[t];
  int lane = t & 63, w = t >> 6;
  int incl = v;
  #pragma unroll
  for (int off = 1; off < 64; off <<= 1) {
    int n = __shfl_up(incl, off, 64);
    if (lane >= off) incl += n;
  }
  __shared__ int ws[4];
  if (lane == 63) ws[w] = incl;
  __syncthreads();
  int wo = 0;
  for (int ww = 0; ww < w; ++ww) wo += ws[ww];
  Dcur[t] = wo + incl - v;
}

__global__ __launch_bounds__(256) void k_dscat(const int* __restrict__ rp,
                                               int* __restrict__ Dcur,
                                               int* __restrict__ nodeorder) {
  __shared__ int lh[256], gbase[256], lcur[256];
  int b = blockIdx.x, t = threadIdx.x;
  lh[t] = 0; lcur[t] = 0;
  __syncthreads();
  int node = b * 256 + t, d = 0;
  if (node < N_NODES) {
    d = rp[node + 1] - rp[node];
    if (d > 255) d = 255;
    atomicAdd(&lh[d], 1);
  }
  __syncthreads();
  if (lh[t]) gbase[t] = atomicAdd(&Dcur[t], lh[t]);
  __syncthreads();
  if (node < N_NODES) {
    int r_ = atomicAdd(&lcur[d], 1);
    nodeorder[gbase[d] + r_] = node;
  }
}

// ---------------- feature conversion / aggregation ----------------

// x f32 -> bf16 into Acat[:,128:256]
__global__ void k_cvt_x(const float* __restrict__ x, short* __restrict__ Acat) {
  int id = blockIdx.x * 256 + threadIdx.x;
  if (id >= N_NODES * 32) return;
  int node = id >> 5, c4 = id & 31;
  float4 v = *(const float4*)(x + (size_t)node * 128 + c4 * 4);
  uint2 u;
  u.x = (unsigned)f2bf(v.x) | ((unsigned)f2bf(v.y) << 16);
  u.y = (unsigned)f2bf(v.z) | ((unsigned)f2bf(v.w) << 16);
  *(uint2*)(Acat + (size_t)node * 256 + 128 + c4 * 4) = u;
}

// Node-per-wave aggregation, degree-sorted for balance.
// Wave w handles node t = nodeorder[w]; the 4 waves of a block have
// near-equal degree -> block time ~ mean, not max-of-4.
// Gathered slice = dwords [GOFF, GOFF+64) of each 256-short source row.
// RESID: add src[t,128:256], write f32 to dst_f32; else bf16 to dst_bf.
template <bool RESID, int GOFF>
__global__ __launch_bounds__(256) void k_agg(const int* __restrict__ rp,
                                             const int* __restrict__ cs,
                                             const int* __restrict__ nodeorder,
                                             const short* __restrict__ src,
                                             short* __restrict__ dst_bf,
                                             float* __restrict__ dst_f32) {
  int wid = blockIdx.x * 4 + (threadIdx.x >> 6);
  if (wid >= N_NODES) return;
  int t = nodeorder[wid];
  int lane = threadIdx.x & 63;
  int s = rp[t], e = rp[t + 1];
  float a0 = 0.f, a1 = 0.f;
  const short* gb = src + GOFF + 2 * lane;
  int i = s;
  for (; i + 8 <= e; i += 8) {
    unsigned u[8];
    #pragma unroll
    for (int q = 0; q < 8; ++q)
      u[q] = *(const unsigned*)(gb + (size_t)cs[i + q] * 256);
    #pragma unroll
    for (int q = 0; q < 8; ++q) {
      a0 += bf2f((unsigned short)u[q]);
      a1 += bf2f((unsigned short)(u[q] >> 16));
    }
  }
  for (; i < e; ++i) {
    unsigned u = *(const unsigned*)(gb + (size_t)cs[i] * 256);
    a0 += bf2f((unsigned short)u);
    a1 += bf2f((unsigned short)(u >> 16));
  }
  if (RESID) {
    unsigned r = *(const unsigned*)(src + (size_t)t * 256 + 128 + 2 * lane);
    a0 += bf2f((unsigned short)r);
    a1 += bf2f((unsigned short)(r >> 16));
    float2 o = {a0, a1};
    *(float2*)(dst_f32 + (size_t)t * 128 + 2 * lane) = o;
  } else {
    *(unsigned*)(dst_bf + (size_t)t * 256 + 2 * lane) =
        (unsigned)f2bf(a0) | ((unsigned)f2bf(a1) << 16);
  }
}

// ---------------- GEMM ----------------

// Fused pack of both weight matrices into MFMA-B fragment layout.
// id < 65536: Bp1 = vstack(Wl1, Wr1) (256x256); else Bp2 = hstack(Wl2, Wr2).
__global__ void k_packs(const float* __restrict__ Wl1, const float* __restrict__ Wr1,
                        const float* __restrict__ Wl2, const float* __restrict__ Wr2,
                        short* __restrict__ Bp1, short* __restrict__ Bp2) {
  int id = blockIdx.x * 256 + threadIdx.x;
  bool second = id >= 65536;
  int lid = id & 65535;
  int j = lid & 7;
  int lane = (lid >> 3) & 63;
  int blk = lid >> 9;
  int nb = blk & 15;
  int kk = blk >> 4;
  int k = kk * 32 + (lane >> 4) * 8 + j;
  int c = nb * 16 + (lane & 15);
  float v;
  if (!second) v = (k < 128) ? Wl1[k * 256 + c] : Wr1[(k - 128) * 256 + c];
  else         v = (c < 128) ? Wl2[k * 128 + c] : Wr2[k * 128 + (c - 128)];
  (second ? Bp2 : Bp1)[lid] = (short)f2bf(v);
}

// C[M x 256] = A[M x 256](bf16) * Bp (+bias per BIAS_MODE), optional relu.
// 128x128 tile, 4 waves 2x2, each wave 64x64 (4x4 16x16x32 frags).
// Grid dim3(2, 784); XCD-chunked bijective decode so both col-halves of a
// row-tile run consecutively on the SAME XCD -> A-tile L2 reuse.
// BIAS_MODE: 0 = bias[colg]; 1 = colg<128 ? 0 : bias[colg-128]
template <int KK, int NBTOT, bool RELU, bool OUT_BF16, int BIAS_MODE>
__global__ __launch_bounds__(256) void k_gemm(const short* __restrict__ A, int lda,
                                              const short* __restrict__ Bp,
                                              const float* __restrict__ bias,
                                              void* __restrict__ out, int ldc,
                                              int mlimit) {
  const int L = blockIdx.x + 2 * blockIdx.y;
  const int xcd = L & 7;
  const int rnd = L >> 3;          // 0..195
  const int colhalf = rnd & 1;
  const int rt = (rnd >> 1) + 98 * xcd;
  if (rt >= MTILES) return;

  const int lane = threadIdx.x & 63;
  const int wave = threadIdx.x >> 6;
  const int wr = wave >> 1, wc = wave & 1;
  const int row0 = rt * 128 + wr * 64;
  const int colbase = colhalf * 128 + wc * 64;
  const int arow = lane & 15;
  const int kgrp = lane >> 4;

  f32x4 acc[4][4];
  const f32x4 zero = {0.f, 0.f, 0.f, 0.f};
  #pragma unroll
  for (int a = 0; a < 4; ++a)
    #pragma unroll
    for (int b = 0; b < 4; ++b) acc[a][b] = zero;

  const short* Bbase = Bp + (size_t)lane * 8;
  for (int kk = 0; kk < KK; ++kk) {
    short8 af[4], bfr[4];
    const int kb = kk * 32 + kgrp * 8;
    #pragma unroll
    for (int mi = 0; mi < 4; ++mi)
      af[mi] = *(const short8*)(A + (size_t)(row0 + mi * 16 + arow) * lda + kb);
    #pragma unroll
    for (int ni = 0; ni < 4; ++ni) {
      int nb = (colbase >> 4) + ni;
      bfr[ni] = *(const short8*)(Bbase + ((size_t)(kk * NBTOT + nb) << 9));
    }
    #pragma unroll
    for (int mi = 0; mi < 4; ++mi)
      #pragma unroll
      for (int ni = 0; ni < 4; ++ni)
        acc[mi][ni] = __builtin_amdgcn_mfma_f32_16x16x32_bf16(af[mi], bfr[ni],
                                                              acc[mi][ni], 0, 0, 0);
  }

  const int ccol = lane & 15;
  const int crow = (lane >> 4) * 4;
  #pragma unroll
  for (int ni = 0; ni < 4; ++ni) {
    const int colg = colbase + ni * 16 + ccol;
    float bv;
    if (BIAS_MODE == 0) bv = bias[colg];
    else bv = (colg < 128) ? 0.f : bias[colg - 128];
    #pragma unroll
    for (int mi = 0; mi < 4; ++mi) {
      #pragma unroll
      for (int j = 0; j < 4; ++j) {
        int rowg = row0 + mi * 16 + crow + j;
        float v = acc[mi][ni][j] + bv;
        if (RELU) v = fmaxf(v, 0.0f);
        if (OUT_BF16) {
          ((short*)out)[(size_t)rowg * ldc + colg] = (short)f2bf(v);
        } else {
          if (rowg < mlimit)
            ((float*)out)[(size_t)rowg * ldc + colg] = v;
        }
      }
    }
  }
}

extern "C" void kernel_launch(void* const* d_in, const int* in_sizes, int n_in,
                              void* d_out, int out_size, void* d_ws, size_t ws_size,
                              hipStream_t stream) {
  const float* x   = (const float*)d_in[0];
  const int*   row = (const int*)d_in[1];
  const int*   col = (const int*)d_in[2];
  const float* Wl1 = (const float*)d_in[3];
  const float* bl1 = (const float*)d_in[4];
  const float* Wr1 = (const float*)d_in[5];
  const float* Wl2 = (const float*)d_in[6];
  const float* bl2 = (const float*)d_in[7];
  const float* Wr2 = (const float*)d_in[8];
  float* out = (float*)d_out;

  char* w = (char*)d_ws;
  auto alloc = [&](size_t bytes) {
    char* p = w;
    w += (bytes + 255) & ~(size_t)255;
    return p;
  };
  short* Acat = (short*)alloc((size_t)MPAD * 256 * 2);  // [agg_x_bf16 | x_bf16]
  short* Hbuf = (short*)alloc((size_t)MPAD * 256 * 2);  // h (post-relu), bf16
  short* P    = (short*)alloc((size_t)MPAD * 256 * 2);  // [h@Wl2 | h@Wr2+bl2], bf16
  short* Bp1  = (short*)alloc(65536 * 2);               // [Wl1;Wr1] packed (vcat)
  short* Bp2  = (short*)alloc(65536 * 2);               // [Wl2|Wr2] packed (hcat)
  int* rp   = (int*)alloc((N_NODES + 1) * 4);
  int* cs   = (int*)alloc((size_t)N_EDGES * 4);
  unsigned* tmp = (unsigned*)alloc((size_t)N_EDGES * 4);
  int* Hc   = (int*)alloc((size_t)NB * NBLK_A * 4);
  int* G    = (int*)alloc((size_t)NB * NBLK_A * 4);
  int* Boff = (int*)alloc((NB + 1) * 4);
  int* Dh   = (int*)alloc(256 * 4);
  int* Dcur = (int*)alloc(256 * 4);
  int* nodeorder = (int*)alloc(N_NODES * 4);

  // --- CSR build: two-level counting sort (no global data atomics) ---
  k_bhist<<<NBLK_A, 256, 0, stream>>>(row, Hc);
  k_bscan<<<1, 512, 0, stream>>>(Hc, Boff, Dh);
  k_bexp<<<NB, 64, 0, stream>>>(Hc, Boff, G);
  k_bscat<<<NBLK_A, 256, 0, stream>>>(row, col, G, tmp);
  k_bsort<<<NB, 256, 0, stream>>>(tmp, Boff, rp, cs);

  // --- degree-sort nodes for balanced agg waves ---
  k_dprep<<<NB, 256, 0, stream>>>(rp, Dh);
  k_dscan<<<1, 256, 0, stream>>>(Dh, Dcur);
  k_dscat<<<NB, 256, 0, stream>>>(rp, Dcur, nodeorder);

  // --- weight packing + x conversion (independent of CSR) ---
  k_cvt_x<<<(N_NODES * 32 + 255) / 256, 256, 0, stream>>>(x, Acat);
  k_packs<<<512, 256, 0, stream>>>(Wl1, Wr1, Wl2, Wr2, Bp1, Bp2);

  // --- layer 1: agg(x) ; h = relu([agg|x] @ [Wl1;Wr1] + bl1) -> Hbuf bf16 ---
  k_agg<false, 128><<<(N_NODES + 3) / 4, 256, 0, stream>>>(
      rp, cs, nodeorder, Acat, Acat, nullptr);
  k_gemm<8, 16, true, true, 0><<<dim3(2, 784), 256, 0, stream>>>(
      Acat, 256, Bp1, bl1, Hbuf, 256, MPAD);

  // --- layer 2: P = h @ [Wl2 | Wr2] (+bl2 on right half) ; out = agg(P_l) + P_r ---
  k_gemm<8, 16, false, true, 1><<<dim3(2, 784), 256, 0, stream>>>(
      Hbuf, 256, Bp2, bl2, P, 256, MPAD);
  k_agg<true, 0><<<(N_NODES + 3) / 4, 256, 0, stream>>>(
      rp, cs, nodeorder, P, nullptr, out);
}

// Round 6
// 286.675 us; speedup vs baseline: 1.1258x; 1.1247x over previous
//
#include <hip/hip_runtime.h>

#define N_NODES 100000
#define N_EDGES 1600000
#define MPAD    100096   /* 782 * 128 */
#define MTILES  782

#define NB      391      /* ceil(100000/256) buckets of 256 nodes */
#define CH      8192     /* edges per phase-A block */
#define NBLK_A  196      /* ceil(1600000/8192) */

typedef __attribute__((ext_vector_type(8))) short short8;
typedef __attribute__((ext_vector_type(4))) float f32x4;

static __device__ __forceinline__ unsigned short f2bf(float f) {
  unsigned u = __builtin_bit_cast(unsigned, f);
  u += 0x7fffu + ((u >> 16) & 1u);     // round-to-nearest-even
  return (unsigned short)(u >> 16);
}
static __device__ __forceinline__ float bf2f(unsigned short s) {
  unsigned u = ((unsigned)s) << 16;
  return __builtin_bit_cast(float, u);
}

// ---------------- CSR build: two-level LDS counting sort ----------------

__global__ __launch_bounds__(256) void k_bhist(const int* __restrict__ row,
                                               int* __restrict__ Hc) {
  __shared__ int hist[NB];
  int b = blockIdx.x, t = threadIdx.x;
  for (int j = t; j < NB; j += 256) hist[j] = 0;
  __syncthreads();
  int base = b * CH;
  #pragma unroll
  for (int k = 0; k < 8; ++k) {
    int i = base + k * 1024 + t * 4;
    if (i < N_EDGES) {
      int4 r = *(const int4*)(row + i);
      atomicAdd(&hist[r.x >> 8], 1);
      atomicAdd(&hist[r.y >> 8], 1);
      atomicAdd(&hist[r.z >> 8], 1);
      atomicAdd(&hist[r.w >> 8], 1);
    }
  }
  __syncthreads();
  for (int j = t; j < NB; j += 256) Hc[j * NBLK_A + b] = hist[j];
}

__global__ __launch_bounds__(512) void k_bscan(const int* __restrict__ Hc,
                                               int* __restrict__ Boff) {
  int t = threadIdx.x;
  int total = 0;
  if (t < NB) {
    const int* p = Hc + t * NBLK_A;
    for (int i = 0; i < NBLK_A; i += 4) {
      int4 v = *(const int4*)(p + i);
      total += v.x + v.y + v.z + v.w;
    }
  }
  int lane = t & 63, w = t >> 6;
  int incl = total;
  #pragma unroll
  for (int off = 1; off < 64; off <<= 1) {
    int n = __shfl_up(incl, off, 64);
    if (lane >= off) incl += n;
  }
  __shared__ int ws[8];
  if (lane == 63) ws[w] = incl;
  __syncthreads();
  int wo = 0;
  for (int ww = 0; ww < w; ++ww) wo += ws[ww];
  int excl = wo + incl - total;
  if (t < NB) Boff[t] = excl;
  if (t == NB - 1) Boff[NB] = excl + total;
}

__global__ __launch_bounds__(64) void k_bexp(const int* __restrict__ Hc,
                                             const int* __restrict__ Boff,
                                             int* __restrict__ G) {
  int b = blockIdx.x, l = threadIdx.x;
  int run = Boff[b];
  const int* p = Hc + b * NBLK_A;
  for (int c = 0; c < NBLK_A; c += 64) {
    int idx = c + l;
    int v = (idx < NBLK_A) ? p[idx] : 0;
    int incl = v;
    #pragma unroll
    for (int off = 1; off < 64; off <<= 1) {
      int n = __shfl_up(incl, off, 64);
      if (l >= off) incl += n;
    }
    if (idx < NBLK_A) G[b * NBLK_A + idx] = run + incl - v;
    run += __shfl(incl, 63, 64);
  }
}

__global__ __launch_bounds__(256) void k_bscat(const int* __restrict__ row,
                                               const int* __restrict__ col,
                                               const int* __restrict__ G,
                                               unsigned* __restrict__ tmp) {
  __shared__ int cur[NB];
  int b = blockIdx.x, t = threadIdx.x;
  for (int j = t; j < NB; j += 256) cur[j] = G[j * NBLK_A + b];
  __syncthreads();
  int base = b * CH;
  #pragma unroll
  for (int k = 0; k < 8; ++k) {
    int i = base + k * 1024 + t * 4;
    if (i < N_EDGES) {
      int4 r = *(const int4*)(row + i);
      int4 c = *(const int4*)(col + i);
      int p0 = atomicAdd(&cur[r.x >> 8], 1);
      tmp[p0] = (unsigned)c.x | ((unsigned)(r.x & 255) << 24);
      int p1 = atomicAdd(&cur[r.y >> 8], 1);
      tmp[p1] = (unsigned)c.y | ((unsigned)(r.y & 255) << 24);
      int p2 = atomicAdd(&cur[r.z >> 8], 1);
      tmp[p2] = (unsigned)c.z | ((unsigned)(r.z & 255) << 24);
      int p3 = atomicAdd(&cur[r.w >> 8], 1);
      tmp[p3] = (unsigned)c.w | ((unsigned)(r.w & 255) << 24);
    }
  }
}

__global__ __launch_bounds__(256) void k_bsort(const unsigned* __restrict__ tmp,
                                               const int* __restrict__ Boff,
                                               int* __restrict__ rp,
                                               int* __restrict__ cs) {
  __shared__ int hist[256];
  __shared__ int wsum[4];
  int b = blockIdx.x, t = threadIdx.x;
  int s = Boff[b], e = Boff[b + 1];
  hist[t] = 0;
  __syncthreads();
  for (int i = s + t; i < e; i += 256) atomicAdd(&hist[tmp[i] >> 24], 1);
  __syncthreads();
  int v = hist[t];
  int lane = t & 63, w = t >> 6;
  int incl = v;
  #pragma unroll
  for (int off = 1; off < 64; off <<= 1) {
    int n = __shfl_up(incl, off, 64);
    if (lane >= off) incl += n;
  }
  if (lane == 63) wsum[w] = incl;
  __syncthreads();
  int wo = 0;
  for (int ww = 0; ww < w; ++ww) wo += wsum[ww];
  int excl = s + wo + incl - v;
  int node = (b << 8) + t;
  if (node < N_NODES) rp[node] = excl;
  __syncthreads();
  hist[t] = excl;    // reuse as cursor
  __syncthreads();
  for (int i = s + t; i < e; i += 256) {
    unsigned u = tmp[i];
    int pos = atomicAdd(&hist[u >> 24], 1);
    cs[pos] = (int)(u & 0xFFFFFFu);
  }
  if (b == 0 && t == 0) rp[N_NODES] = N_EDGES;
}

// ---------------- feature conversion / aggregation ----------------

// x f32 -> bf16 into Acat[:,128:256]
__global__ void k_cvt_x(const float* __restrict__ x, short* __restrict__ Acat) {
  int id = blockIdx.x * 256 + threadIdx.x;
  if (id >= N_NODES * 32) return;
  int node = id >> 5, c4 = id & 31;
  float4 v = *(const float4*)(x + (size_t)node * 128 + c4 * 4);
  uint2 u;
  u.x = (unsigned)f2bf(v.x) | ((unsigned)f2bf(v.y) << 16);
  u.y = (unsigned)f2bf(v.z) | ((unsigned)f2bf(v.w) << 16);
  *(uint2*)(Acat + (size_t)node * 256 + 128 + c4 * 4) = u;
}

// Node-per-wave aggregation, deep-MLP: 16 gathers always in flight.
// Full rounds are unpredicated; the ragged last round issues 16 CLAMPED
// loads (clamped lanes re-read the last edge's row -> L1/L2 hit, ~free)
// with predicated accumulate. No serial tail, ever.
// Gathered slice = dwords [GOFF, GOFF+64) of each 256-short source row.
// RESID: add src[t,128:256], write f32 to dst_f32; else bf16 to dst_bf.
template <bool RESID, int GOFF>
__global__ __launch_bounds__(256) void k_agg(const int* __restrict__ rp,
                                             const int* __restrict__ cs,
                                             const short* __restrict__ src,
                                             short* __restrict__ dst_bf,
                                             float* __restrict__ dst_f32) {
  int t = blockIdx.x * 4 + (threadIdx.x >> 6);
  if (t >= N_NODES) return;
  int lane = threadIdx.x & 63;
  int s = rp[t], e = rp[t + 1];
  float a0 = 0.f, a1 = 0.f;
  const short* gb = src + GOFF + 2 * lane;
  int i = s;
  for (; i + 16 <= e; i += 16) {
    unsigned u[16];
    #pragma unroll
    for (int q = 0; q < 16; ++q)
      u[q] = *(const unsigned*)(gb + (size_t)cs[i + q] * 256);
    #pragma unroll
    for (int q = 0; q < 16; ++q) {
      a0 += bf2f((unsigned short)u[q]);
      a1 += bf2f((unsigned short)(u[q] >> 16));
    }
  }
  if (i < e) {
    unsigned u[16];
    #pragma unroll
    for (int q = 0; q < 16; ++q) {
      int j = (i + q < e) ? (i + q) : (e - 1);
      u[q] = *(const unsigned*)(gb + (size_t)cs[j] * 256);
    }
    #pragma unroll
    for (int q = 0; q < 16; ++q) {
      if (i + q < e) {
        a0 += bf2f((unsigned short)u[q]);
        a1 += bf2f((unsigned short)(u[q] >> 16));
      }
    }
  }
  if (RESID) {
    unsigned r = *(const unsigned*)(src + (size_t)t * 256 + 128 + 2 * lane);
    a0 += bf2f((unsigned short)r);
    a1 += bf2f((unsigned short)(r >> 16));
    float2 o = {a0, a1};
    *(float2*)(dst_f32 + (size_t)t * 128 + 2 * lane) = o;
  } else {
    *(unsigned*)(dst_bf + (size_t)t * 256 + 2 * lane) =
        (unsigned)f2bf(a0) | ((unsigned)f2bf(a1) << 16);
  }
}

// ---------------- GEMM ----------------

// Fused pack of both weight matrices into MFMA-B fragment layout.
// id < 65536: Bp1 = vstack(Wl1, Wr1) (256x256); else Bp2 = hstack(Wl2, Wr2).
__global__ void k_packs(const float* __restrict__ Wl1, const float* __restrict__ Wr1,
                        const float* __restrict__ Wl2, const float* __restrict__ Wr2,
                        short* __restrict__ Bp1, short* __restrict__ Bp2) {
  int id = blockIdx.x * 256 + threadIdx.x;
  bool second = id >= 65536;
  int lid = id & 65535;
  int j = lid & 7;
  int lane = (lid >> 3) & 63;
  int blk = lid >> 9;
  int nb = blk & 15;
  int kk = blk >> 4;
  int k = kk * 32 + (lane >> 4) * 8 + j;
  int c = nb * 16 + (lane & 15);
  float v;
  if (!second) v = (k < 128) ? Wl1[k * 256 + c] : Wr1[(k - 128) * 256 + c];
  else         v = (c < 128) ? Wl2[k * 128 + c] : Wr2[k * 128 + (c - 128)];
  (second ? Bp2 : Bp1)[lid] = (short)f2bf(v);
}

// C[M x 256] = A[M x 256](bf16) * Bp (+bias per BIAS_MODE), optional relu.
// 128x128 tile, 4 waves 2x2, each wave 64x64 (4x4 16x16x32 frags).
// Grid dim3(2, 784); XCD-chunked bijective decode so both col-halves of a
// row-tile run consecutively on the SAME XCD -> A-tile L2 reuse.
// BIAS_MODE: 0 = bias[colg]; 1 = colg<128 ? 0 : bias[colg-128]
template <int KK, int NBTOT, bool RELU, bool OUT_BF16, int BIAS_MODE>
__global__ __launch_bounds__(256) void k_gemm(const short* __restrict__ A, int lda,
                                              const short* __restrict__ Bp,
                                              const float* __restrict__ bias,
                                              void* __restrict__ out, int ldc,
                                              int mlimit) {
  const int L = blockIdx.x + 2 * blockIdx.y;
  const int xcd = L & 7;
  const int rnd = L >> 3;          // 0..195
  const int colhalf = rnd & 1;
  const int rt = (rnd >> 1) + 98 * xcd;
  if (rt >= MTILES) return;

  const int lane = threadIdx.x & 63;
  const int wave = threadIdx.x >> 6;
  const int wr = wave >> 1, wc = wave & 1;
  const int row0 = rt * 128 + wr * 64;
  const int colbase = colhalf * 128 + wc * 64;
  const int arow = lane & 15;
  const int kgrp = lane >> 4;

  f32x4 acc[4][4];
  const f32x4 zero = {0.f, 0.f, 0.f, 0.f};
  #pragma unroll
  for (int a = 0; a < 4; ++a)
    #pragma unroll
    for (int b = 0; b < 4; ++b) acc[a][b] = zero;

  const short* Bbase = Bp + (size_t)lane * 8;
  for (int kk = 0; kk < KK; ++kk) {
    short8 af[4], bfr[4];
    const int kb = kk * 32 + kgrp * 8;
    #pragma unroll
    for (int mi = 0; mi < 4; ++mi)
      af[mi] = *(const short8*)(A + (size_t)(row0 + mi * 16 + arow) * lda + kb);
    #pragma unroll
    for (int ni = 0; ni < 4; ++ni) {
      int nb = (colbase >> 4) + ni;
      bfr[ni] = *(const short8*)(Bbase + ((size_t)(kk * NBTOT + nb) << 9));
    }
    #pragma unroll
    for (int mi = 0; mi < 4; ++mi)
      #pragma unroll
      for (int ni = 0; ni < 4; ++ni)
        acc[mi][ni] = __builtin_amdgcn_mfma_f32_16x16x32_bf16(af[mi], bfr[ni],
                                                              acc[mi][ni], 0, 0, 0);
  }

  const int ccol = lane & 15;
  const int crow = (lane >> 4) * 4;
  #pragma unroll
  for (int ni = 0; ni < 4; ++ni) {
    const int colg = colbase + ni * 16 + ccol;
    float bv;
    if (BIAS_MODE == 0) bv = bias[colg];
    else bv = (colg < 128) ? 0.f : bias[colg - 128];
    #pragma unroll
    for (int mi = 0; mi < 4; ++mi) {
      #pragma unroll
      for (int j = 0; j < 4; ++j) {
        int rowg = row0 + mi * 16 + crow + j;
        float v = acc[mi][ni][j] + bv;
        if (RELU) v = fmaxf(v, 0.0f);
        if (OUT_BF16) {
          ((short*)out)[(size_t)rowg * ldc + colg] = (short)f2bf(v);
        } else {
          if (rowg < mlimit)
            ((float*)out)[(size_t)rowg * ldc + colg] = v;
        }
      }
    }
  }
}

extern "C" void kernel_launch(void* const* d_in, const int* in_sizes, int n_in,
                              void* d_out, int out_size, void* d_ws, size_t ws_size,
                              hipStream_t stream) {
  const float* x   = (const float*)d_in[0];
  const int*   row = (const int*)d_in[1];
  const int*   col = (const int*)d_in[2];
  const float* Wl1 = (const float*)d_in[3];
  const float* bl1 = (const float*)d_in[4];
  const float* Wr1 = (const float*)d_in[5];
  const float* Wl2 = (const float*)d_in[6];
  const float* bl2 = (const float*)d_in[7];
  const float* Wr2 = (const float*)d_in[8];
  float* out = (float*)d_out;

  char* w = (char*)d_ws;
  auto alloc = [&](size_t bytes) {
    char* p = w;
    w += (bytes + 255) & ~(size_t)255;
    return p;
  };
  short* Acat = (short*)alloc((size_t)MPAD * 256 * 2);  // [agg_x_bf16 | x_bf16]
  short* Hbuf = (short*)alloc((size_t)MPAD * 256 * 2);  // h (post-relu), bf16
  short* P    = (short*)alloc((size_t)MPAD * 256 * 2);  // [h@Wl2 | h@Wr2+bl2], bf16
  short* Bp1  = (short*)alloc(65536 * 2);               // [Wl1;Wr1] packed (vcat)
  short* Bp2  = (short*)alloc(65536 * 2);               // [Wl2|Wr2] packed (hcat)
  int* rp   = (int*)alloc((N_NODES + 1) * 4);
  int* cs   = (int*)alloc((size_t)N_EDGES * 4);
  unsigned* tmp = (unsigned*)alloc((size_t)N_EDGES * 4);
  int* Hc   = (int*)alloc((size_t)NB * NBLK_A * 4);
  int* G    = (int*)alloc((size_t)NB * NBLK_A * 4);
  int* Boff = (int*)alloc((NB + 1) * 4);

  // --- CSR build: two-level counting sort (no global data atomics) ---
  k_bhist<<<NBLK_A, 256, 0, stream>>>(row, Hc);
  k_bscan<<<1, 512, 0, stream>>>(Hc, Boff);
  k_bexp<<<NB, 64, 0, stream>>>(Hc, Boff, G);
  k_bscat<<<NBLK_A, 256, 0, stream>>>(row, col, G, tmp);
  k_bsort<<<NB, 256, 0, stream>>>(tmp, Boff, rp, cs);

  // --- weight packing + x conversion (independent of CSR) ---
  k_cvt_x<<<(N_NODES * 32 + 255) / 256, 256, 0, stream>>>(x, Acat);
  k_packs<<<512, 256, 0, stream>>>(Wl1, Wr1, Wl2, Wr2, Bp1, Bp2);

  // --- layer 1: agg(x) ; h = relu([agg|x] @ [Wl1;Wr1] + bl1) -> Hbuf bf16 ---
  k_agg<false, 128><<<(N_NODES + 3) / 4, 256, 0, stream>>>(
      rp, cs, Acat, Acat, nullptr);
  k_gemm<8, 16, true, true, 0><<<dim3(2, 784), 256, 0, stream>>>(
      Acat, 256, Bp1, bl1, Hbuf, 256, MPAD);

  // --- layer 2: P = h @ [Wl2 | Wr2] (+bl2 on right half) ; out = agg(P_l) + P_r ---
  k_gemm<8, 16, false, true, 1><<<dim3(2, 784), 256, 0, stream>>>(
      Hbuf, 256, Bp2, bl2, P, 256, MPAD);
  k_agg<true, 0><<<(N_NODES + 3) / 4, 256, 0, stream>>>(
      rp, cs, P, nullptr, out);
}

// Round 7
// 279.488 us; speedup vs baseline: 1.1548x; 1.0257x over previous
//
#include <hip/hip_runtime.h>

#define N_NODES 100000
#define N_EDGES 1600000
#define MPAD    100096   /* 782 * 128 */
#define MTILES  782

#define NB      391      /* ceil(100000/256) buckets of 256 nodes */
#define CH      8192     /* edges per phase-A block */
#define NBLK_A  196      /* ceil(1600000/8192) */

typedef __attribute__((ext_vector_type(8))) short short8;
typedef __attribute__((ext_vector_type(4))) float f32x4;

static __device__ __forceinline__ unsigned short f2bf(float f) {
  unsigned u = __builtin_bit_cast(unsigned, f);
  u += 0x7fffu + ((u >> 16) & 1u);     // round-to-nearest-even
  return (unsigned short)(u >> 16);
}
static __device__ __forceinline__ float bf2f(unsigned short s) {
  unsigned u = ((unsigned)s) << 16;
  return __builtin_bit_cast(float, u);
}

// ---------------- CSR build: two-level LDS counting sort ----------------

__global__ __launch_bounds__(256) void k_bhist(const int* __restrict__ row,
                                               int* __restrict__ Hc) {
  __shared__ int hist[NB];
  int b = blockIdx.x, t = threadIdx.x;
  for (int j = t; j < NB; j += 256) hist[j] = 0;
  __syncthreads();
  int base = b * CH;
  #pragma unroll
  for (int k = 0; k < 8; ++k) {
    int i = base + k * 1024 + t * 4;
    if (i < N_EDGES) {
      int4 r = *(const int4*)(row + i);
      atomicAdd(&hist[r.x >> 8], 1);
      atomicAdd(&hist[r.y >> 8], 1);
      atomicAdd(&hist[r.z >> 8], 1);
      atomicAdd(&hist[r.w >> 8], 1);
    }
  }
  __syncthreads();
  for (int j = t; j < NB; j += 256) Hc[j * NBLK_A + b] = hist[j];
}

__global__ __launch_bounds__(512) void k_bscan(const int* __restrict__ Hc,
                                               int* __restrict__ Boff) {
  int t = threadIdx.x;
  int total = 0;
  if (t < NB) {
    const int* p = Hc + t * NBLK_A;
    for (int i = 0; i < NBLK_A; i += 4) {
      int4 v = *(const int4*)(p + i);
      total += v.x + v.y + v.z + v.w;
    }
  }
  int lane = t & 63, w = t >> 6;
  int incl = total;
  #pragma unroll
  for (int off = 1; off < 64; off <<= 1) {
    int n = __shfl_up(incl, off, 64);
    if (lane >= off) incl += n;
  }
  __shared__ int ws[8];
  if (lane == 63) ws[w] = incl;
  __syncthreads();
  int wo = 0;
  for (int ww = 0; ww < w; ++ww) wo += ws[ww];
  int excl = wo + incl - total;
  if (t < NB) Boff[t] = excl;
  if (t == NB - 1) Boff[NB] = excl + total;
}

__global__ __launch_bounds__(64) void k_bexp(const int* __restrict__ Hc,
                                             const int* __restrict__ Boff,
                                             int* __restrict__ G) {
  int b = blockIdx.x, l = threadIdx.x;
  int run = Boff[b];
  const int* p = Hc + b * NBLK_A;
  for (int c = 0; c < NBLK_A; c += 64) {
    int idx = c + l;
    int v = (idx < NBLK_A) ? p[idx] : 0;
    int incl = v;
    #pragma unroll
    for (int off = 1; off < 64; off <<= 1) {
      int n = __shfl_up(incl, off, 64);
      if (l >= off) incl += n;
    }
    if (idx < NBLK_A) G[b * NBLK_A + idx] = run + incl - v;
    run += __shfl(incl, 63, 64);
  }
}

__global__ __launch_bounds__(256) void k_bscat(const int* __restrict__ row,
                                               const int* __restrict__ col,
                                               const int* __restrict__ G,
                                               unsigned* __restrict__ tmp) {
  __shared__ int cur[NB];
  int b = blockIdx.x, t = threadIdx.x;
  for (int j = t; j < NB; j += 256) cur[j] = G[j * NBLK_A + b];
  __syncthreads();
  int base = b * CH;
  #pragma unroll
  for (int k = 0; k < 8; ++k) {
    int i = base + k * 1024 + t * 4;
    if (i < N_EDGES) {
      int4 r = *(const int4*)(row + i);
      int4 c = *(const int4*)(col + i);
      int p0 = atomicAdd(&cur[r.x >> 8], 1);
      tmp[p0] = (unsigned)c.x | ((unsigned)(r.x & 255) << 24);
      int p1 = atomicAdd(&cur[r.y >> 8], 1);
      tmp[p1] = (unsigned)c.y | ((unsigned)(r.y & 255) << 24);
      int p2 = atomicAdd(&cur[r.z >> 8], 1);
      tmp[p2] = (unsigned)c.z | ((unsigned)(r.z & 255) << 24);
      int p3 = atomicAdd(&cur[r.w >> 8], 1);
      tmp[p3] = (unsigned)c.w | ((unsigned)(r.w & 255) << 24);
    }
  }
}

__global__ __launch_bounds__(256) void k_bsort(const unsigned* __restrict__ tmp,
                                               const int* __restrict__ Boff,
                                               int* __restrict__ rp,
                                               int* __restrict__ cs) {
  __shared__ int hist[256];
  __shared__ int wsum[4];
  int b = blockIdx.x, t = threadIdx.x;
  int s = Boff[b], e = Boff[b + 1];
  hist[t] = 0;
  __syncthreads();
  for (int i = s + t; i < e; i += 256) atomicAdd(&hist[tmp[i] >> 24], 1);
  __syncthreads();
  int v = hist[t];
  int lane = t & 63, w = t >> 6;
  int incl = v;
  #pragma unroll
  for (int off = 1; off < 64; off <<= 1) {
    int n = __shfl_up(incl, off, 64);
    if (lane >= off) incl += n;
  }
  if (lane == 63) wsum[w] = incl;
  __syncthreads();
  int wo = 0;
  for (int ww = 0; ww < w; ++ww) wo += wsum[ww];
  int excl = s + wo + incl - v;
  int node = (b << 8) + t;
  if (node < N_NODES) rp[node] = excl;
  __syncthreads();
  hist[t] = excl;    // reuse as cursor
  __syncthreads();
  for (int i = s + t; i < e; i += 256) {
    unsigned u = tmp[i];
    int pos = atomicAdd(&hist[u >> 24], 1);
    cs[pos] = (int)(u & 0xFFFFFFu);
  }
  if (b == 0 && t == 0) rp[N_NODES] = N_EDGES;
}

// ---------------- feature conversion / aggregation ----------------

// x f32 -> bf16 into Acat[:,128:256]
__global__ void k_cvt_x(const float* __restrict__ x, short* __restrict__ Acat) {
  int id = blockIdx.x * 256 + threadIdx.x;
  if (id >= N_NODES * 32) return;
  int node = id >> 5, c4 = id & 31;
  float4 v = *(const float4*)(x + (size_t)node * 128 + c4 * 4);
  uint2 u;
  u.x = (unsigned)f2bf(v.x) | ((unsigned)f2bf(v.y) << 16);
  u.y = (unsigned)f2bf(v.z) | ((unsigned)f2bf(v.w) << 16);
  *(uint2*)(Acat + (size_t)node * 256 + 128 + c4 * 4) = u;
}

// Node-per-wave aggregation, scalarized uniform path + tail-correction.
// Node id readfirstlane'd -> rp/cs loads, indices, gather bases are all
// SGPR/SALU/s_load; per-edge VALU = 2 cvt + 2 add only.
// Unified loop: ceil(d/16) rounds of 16 CLAMPED gathers (clamp j=min(j,e-1)
// is scalar), unconditional accumulate; then subtract over*row[e-1] once
// (exact product, over<=15; rounding delta ~ulps, irrelevant vs threshold).
// Gathered slice = dwords [GOFF, GOFF+64) of each 256-short source row.
// RESID: add src[t,128:256], write f32 to dst_f32; else bf16 to dst_bf.
template <bool RESID, int GOFF>
__global__ __launch_bounds__(256) void k_agg(const int* __restrict__ rp,
                                             const int* __restrict__ cs,
                                             const short* __restrict__ src,
                                             short* __restrict__ dst_bf,
                                             float* __restrict__ dst_f32) {
  const int t = __builtin_amdgcn_readfirstlane(blockIdx.x * 4 + (threadIdx.x >> 6));
  if (t >= N_NODES) return;
  const int lane = threadIdx.x & 63;
  const int s = rp[t], e = rp[t + 1];
  const int d = e - s;
  float a0 = 0.f, a1 = 0.f;
  const short* gb = src + GOFF + 2 * lane;
  if (d > 0) {
    const int last = e - 1;
    const int rounds = (d + 15) >> 4;
    for (int r = 0; r < rounds; ++r) {
      int base = s + (r << 4);
      unsigned u[16];
      #pragma unroll
      for (int q = 0; q < 16; ++q) {
        int j = base + q;
        j = (j < last) ? j : last;                       // wave-uniform clamp
        u[q] = *(const unsigned*)(gb + (size_t)cs[j] * 256);
      }
      #pragma unroll
      for (int q = 0; q < 16; ++q) {
        a0 += bf2f((unsigned short)u[q]);
        a1 += bf2f((unsigned short)(u[q] >> 16));
      }
    }
    const int over = (rounds << 4) - d;
    if (over) {
      unsigned ul = *(const unsigned*)(gb + (size_t)cs[last] * 256);
      float c = (float)over;
      a0 -= c * bf2f((unsigned short)ul);
      a1 -= c * bf2f((unsigned short)(ul >> 16));
    }
  }
  if (RESID) {
    unsigned r = *(const unsigned*)(src + (size_t)t * 256 + 128 + 2 * lane);
    a0 += bf2f((unsigned short)r);
    a1 += bf2f((unsigned short)(r >> 16));
    float2 o = {a0, a1};
    *(float2*)(dst_f32 + (size_t)t * 128 + 2 * lane) = o;
  } else {
    *(unsigned*)(dst_bf + (size_t)t * 256 + 2 * lane) =
        (unsigned)f2bf(a0) | ((unsigned)f2bf(a1) << 16);
  }
}

// ---------------- GEMM ----------------

// Fused pack of both weight matrices into MFMA-B fragment layout.
// id < 65536: Bp1 = vstack(Wl1, Wr1) (256x256); else Bp2 = hstack(Wl2, Wr2).
__global__ void k_packs(const float* __restrict__ Wl1, const float* __restrict__ Wr1,
                        const float* __restrict__ Wl2, const float* __restrict__ Wr2,
                        short* __restrict__ Bp1, short* __restrict__ Bp2) {
  int id = blockIdx.x * 256 + threadIdx.x;
  bool second = id >= 65536;
  int lid = id & 65535;
  int j = lid & 7;
  int lane = (lid >> 3) & 63;
  int blk = lid >> 9;
  int nb = blk & 15;
  int kk = blk >> 4;
  int k = kk * 32 + (lane >> 4) * 8 + j;
  int c = nb * 16 + (lane & 15);
  float v;
  if (!second) v = (k < 128) ? Wl1[k * 256 + c] : Wr1[(k - 128) * 256 + c];
  else         v = (c < 128) ? Wl2[k * 128 + c] : Wr2[k * 128 + (c - 128)];
  (second ? Bp2 : Bp1)[lid] = (short)f2bf(v);
}

// C[M x 256] = A[M x 256](bf16) * Bp (+bias per BIAS_MODE), optional relu.
// 128x128 tile, 4 waves 2x2, each wave 64x64 (4x4 16x16x32 frags).
// Grid dim3(2, 784); XCD-chunked bijective decode so both col-halves of a
// row-tile run consecutively on the SAME XCD -> A-tile L2 reuse.
// BIAS_MODE: 0 = bias[colg]; 1 = colg<128 ? 0 : bias[colg-128]
template <int KK, int NBTOT, bool RELU, bool OUT_BF16, int BIAS_MODE>
__global__ __launch_bounds__(256) void k_gemm(const short* __restrict__ A, int lda,
                                              const short* __restrict__ Bp,
                                              const float* __restrict__ bias,
                                              void* __restrict__ out, int ldc,
                                              int mlimit) {
  const int L = blockIdx.x + 2 * blockIdx.y;
  const int xcd = L & 7;
  const int rnd = L >> 3;          // 0..195
  const int colhalf = rnd & 1;
  const int rt = (rnd >> 1) + 98 * xcd;
  if (rt >= MTILES) return;

  const int lane = threadIdx.x & 63;
  const int wave = threadIdx.x >> 6;
  const int wr = wave >> 1, wc = wave & 1;
  const int row0 = rt * 128 + wr * 64;
  const int colbase = colhalf * 128 + wc * 64;
  const int arow = lane & 15;
  const int kgrp = lane >> 4;

  f32x4 acc[4][4];
  const f32x4 zero = {0.f, 0.f, 0.f, 0.f};
  #pragma unroll
  for (int a = 0; a < 4; ++a)
    #pragma unroll
    for (int b = 0; b < 4; ++b) acc[a][b] = zero;

  const short* Bbase = Bp + (size_t)lane * 8;
  for (int kk = 0; kk < KK; ++kk) {
    short8 af[4], bfr[4];
    const int kb = kk * 32 + kgrp * 8;
    #pragma unroll
    for (int mi = 0; mi < 4; ++mi)
      af[mi] = *(const short8*)(A + (size_t)(row0 + mi * 16 + arow) * lda + kb);
    #pragma unroll
    for (int ni = 0; ni < 4; ++ni) {
      int nb = (colbase >> 4) + ni;
      bfr[ni] = *(const short8*)(Bbase + ((size_t)(kk * NBTOT + nb) << 9));
    }
    #pragma unroll
    for (int mi = 0; mi < 4; ++mi)
      #pragma unroll
      for (int ni = 0; ni < 4; ++ni)
        acc[mi][ni] = __builtin_amdgcn_mfma_f32_16x16x32_bf16(af[mi], bfr[ni],
                                                              acc[mi][ni], 0, 0, 0);
  }

  const int ccol = lane & 15;
  const int crow = (lane >> 4) * 4;
  #pragma unroll
  for (int ni = 0; ni < 4; ++ni) {
    const int colg = colbase + ni * 16 + ccol;
    float bv;
    if (BIAS_MODE == 0) bv = bias[colg];
    else bv = (colg < 128) ? 0.f : bias[colg - 128];
    #pragma unroll
    for (int mi = 0; mi < 4; ++mi) {
      #pragma unroll
      for (int j = 0; j < 4; ++j) {
        int rowg = row0 + mi * 16 + crow + j;
        float v = acc[mi][ni][j] + bv;
        if (RELU) v = fmaxf(v, 0.0f);
        if (OUT_BF16) {
          ((short*)out)[(size_t)rowg * ldc + colg] = (short)f2bf(v);
        } else {
          if (rowg < mlimit)
            ((float*)out)[(size_t)rowg * ldc + colg] = v;
        }
      }
    }
  }
}

extern "C" void kernel_launch(void* const* d_in, const int* in_sizes, int n_in,
                              void* d_out, int out_size, void* d_ws, size_t ws_size,
                              hipStream_t stream) {
  const float* x   = (const float*)d_in[0];
  const int*   row = (const int*)d_in[1];
  const int*   col = (const int*)d_in[2];
  const float* Wl1 = (const float*)d_in[3];
  const float* bl1 = (const float*)d_in[4];
  const float* Wr1 = (const float*)d_in[5];
  const float* Wl2 = (const float*)d_in[6];
  const float* bl2 = (const float*)d_in[7];
  const float* Wr2 = (const float*)d_in[8];
  float* out = (float*)d_out;

  char* w = (char*)d_ws;
  auto alloc = [&](size_t bytes) {
    char* p = w;
    w += (bytes + 255) & ~(size_t)255;
    return p;
  };
  short* Acat = (short*)alloc((size_t)MPAD * 256 * 2);  // [agg_x_bf16 | x_bf16]
  short* Hbuf = (short*)alloc((size_t)MPAD * 256 * 2);  // h (post-relu), bf16
  short* P    = (short*)alloc((size_t)MPAD * 256 * 2);  // [h@Wl2 | h@Wr2+bl2], bf16
  short* Bp1  = (short*)alloc(65536 * 2);               // [Wl1;Wr1] packed (vcat)
  short* Bp2  = (short*)alloc(65536 * 2);               // [Wl2|Wr2] packed (hcat)
  int* rp   = (int*)alloc((N_NODES + 1) * 4);
  int* cs   = (int*)alloc((size_t)N_EDGES * 4);
  unsigned* tmp = (unsigned*)alloc((size_t)N_EDGES * 4);
  int* Hc   = (int*)alloc((size_t)NB * NBLK_A * 4);
  int* G    = (int*)alloc((size_t)NB * NBLK_A * 4);
  int* Boff = (int*)alloc((NB + 1) * 4);

  // --- CSR build: two-level counting sort (no global data atomics) ---
  k_bhist<<<NBLK_A, 256, 0, stream>>>(row, Hc);
  k_bscan<<<1, 512, 0, stream>>>(Hc, Boff);
  k_bexp<<<NB, 64, 0, stream>>>(Hc, Boff, G);
  k_bscat<<<NBLK_A, 256, 0, stream>>>(row, col, G, tmp);
  k_bsort<<<NB, 256, 0, stream>>>(tmp, Boff, rp, cs);

  // --- weight packing + x conversion (independent of CSR) ---
  k_cvt_x<<<(N_NODES * 32 + 255) / 256, 256, 0, stream>>>(x, Acat);
  k_packs<<<512, 256, 0, stream>>>(Wl1, Wr1, Wl2, Wr2, Bp1, Bp2);

  // --- layer 1: agg(x) ; h = relu([agg|x] @ [Wl1;Wr1] + bl1) -> Hbuf bf16 ---
  k_agg<false, 128><<<(N_NODES + 3) / 4, 256, 0, stream>>>(
      rp, cs, Acat, Acat, nullptr);
  k_gemm<8, 16, true, true, 0><<<dim3(2, 784), 256, 0, stream>>>(
      Acat, 256, Bp1, bl1, Hbuf, 256, MPAD);

  // --- layer 2: P = h @ [Wl2 | Wr2] (+bl2 on right half) ; out = agg(P_l) + P_r ---
  k_gemm<8, 16, false, true, 1><<<dim3(2, 784), 256, 0, stream>>>(
      Hbuf, 256, Bp2, bl2, P, 256, MPAD);
  k_agg<true, 0><<<(N_NODES + 3) / 4, 256, 0, stream>>>(
      rp, cs, P, nullptr, out);
}

// Round 8
// 278.619 us; speedup vs baseline: 1.1584x; 1.0031x over previous
//
#include <hip/hip_runtime.h>

#define N_NODES 100000
#define N_EDGES 1600000
#define MPAD    100096   /* 782 * 128 */
#define MTILES  782

#define NB      391      /* ceil(100000/256) buckets of 256 nodes */
#define CH      8192     /* edges per phase-A block */
#define NBLK_A  196      /* ceil(1600000/8192) */

typedef __attribute__((ext_vector_type(8))) short short8;
typedef __attribute__((ext_vector_type(4))) float f32x4;

static __device__ __forceinline__ unsigned short f2bf(float f) {
  unsigned u = __builtin_bit_cast(unsigned, f);
  u += 0x7fffu + ((u >> 16) & 1u);     // round-to-nearest-even
  return (unsigned short)(u >> 16);
}
static __device__ __forceinline__ float bf2f(unsigned short s) {
  unsigned u = ((unsigned)s) << 16;
  return __builtin_bit_cast(float, u);
}

// ---------------- CSR build: two-level LDS counting sort ----------------

__global__ __launch_bounds__(256) void k_bhist(const int* __restrict__ row,
                                               int* __restrict__ Hc) {
  __shared__ int hist[NB];
  int b = blockIdx.x, t = threadIdx.x;
  for (int j = t; j < NB; j += 256) hist[j] = 0;
  __syncthreads();
  int base = b * CH;
  #pragma unroll
  for (int k = 0; k < 8; ++k) {
    int i = base + k * 1024 + t * 4;
    if (i < N_EDGES) {
      int4 r = *(const int4*)(row + i);
      atomicAdd(&hist[r.x >> 8], 1);
      atomicAdd(&hist[r.y >> 8], 1);
      atomicAdd(&hist[r.z >> 8], 1);
      atomicAdd(&hist[r.w >> 8], 1);
    }
  }
  __syncthreads();
  for (int j = t; j < NB; j += 256) Hc[j * NBLK_A + b] = hist[j];
}

__global__ __launch_bounds__(512) void k_bscan(const int* __restrict__ Hc,
                                               int* __restrict__ Boff) {
  int t = threadIdx.x;
  int total = 0;
  if (t < NB) {
    const int* p = Hc + t * NBLK_A;
    for (int i = 0; i < NBLK_A; i += 4) {
      int4 v = *(const int4*)(p + i);
      total += v.x + v.y + v.z + v.w;
    }
  }
  int lane = t & 63, w = t >> 6;
  int incl = total;
  #pragma unroll
  for (int off = 1; off < 64; off <<= 1) {
    int n = __shfl_up(incl, off, 64);
    if (lane >= off) incl += n;
  }
  __shared__ int ws[8];
  if (lane == 63) ws[w] = incl;
  __syncthreads();
  int wo = 0;
  for (int ww = 0; ww < w; ++ww) wo += ws[ww];
  int excl = wo + incl - total;
  if (t < NB) Boff[t] = excl;
  if (t == NB - 1) Boff[NB] = excl + total;
}

__global__ __launch_bounds__(64) void k_bexp(const int* __restrict__ Hc,
                                             const int* __restrict__ Boff,
                                             int* __restrict__ G) {
  int b = blockIdx.x, l = threadIdx.x;
  int run = Boff[b];
  const int* p = Hc + b * NBLK_A;
  for (int c = 0; c < NBLK_A; c += 64) {
    int idx = c + l;
    int v = (idx < NBLK_A) ? p[idx] : 0;
    int incl = v;
    #pragma unroll
    for (int off = 1; off < 64; off <<= 1) {
      int n = __shfl_up(incl, off, 64);
      if (l >= off) incl += n;
    }
    if (idx < NBLK_A) G[b * NBLK_A + idx] = run + incl - v;
    run += __shfl(incl, 63, 64);
  }
}

__global__ __launch_bounds__(256) void k_bscat(const int* __restrict__ row,
                                               const int* __restrict__ col,
                                               const int* __restrict__ G,
                                               unsigned* __restrict__ tmp) {
  __shared__ int cur[NB];
  int b = blockIdx.x, t = threadIdx.x;
  for (int j = t; j < NB; j += 256) cur[j] = G[j * NBLK_A + b];
  __syncthreads();
  int base = b * CH;
  #pragma unroll
  for (int k = 0; k < 8; ++k) {
    int i = base + k * 1024 + t * 4;
    if (i < N_EDGES) {
      int4 r = *(const int4*)(row + i);
      int4 c = *(const int4*)(col + i);
      int p0 = atomicAdd(&cur[r.x >> 8], 1);
      tmp[p0] = (unsigned)c.x | ((unsigned)(r.x & 255) << 24);
      int p1 = atomicAdd(&cur[r.y >> 8], 1);
      tmp[p1] = (unsigned)c.y | ((unsigned)(r.y & 255) << 24);
      int p2 = atomicAdd(&cur[r.z >> 8], 1);
      tmp[p2] = (unsigned)c.z | ((unsigned)(r.z & 255) << 24);
      int p3 = atomicAdd(&cur[r.w >> 8], 1);
      tmp[p3] = (unsigned)c.w | ((unsigned)(r.w & 255) << 24);
    }
  }
}

__global__ __launch_bounds__(256) void k_bsort(const unsigned* __restrict__ tmp,
                                               const int* __restrict__ Boff,
                                               int* __restrict__ rp,
                                               int* __restrict__ cs) {
  __shared__ int hist[256];
  __shared__ int wsum[4];
  int b = blockIdx.x, t = threadIdx.x;
  int s = Boff[b], e = Boff[b + 1];
  hist[t] = 0;
  __syncthreads();
  for (int i = s + t; i < e; i += 256) atomicAdd(&hist[tmp[i] >> 24], 1);
  __syncthreads();
  int v = hist[t];
  int lane = t & 63, w = t >> 6;
  int incl = v;
  #pragma unroll
  for (int off = 1; off < 64; off <<= 1) {
    int n = __shfl_up(incl, off, 64);
    if (lane >= off) incl += n;
  }
  if (lane == 63) wsum[w] = incl;
  __syncthreads();
  int wo = 0;
  for (int ww = 0; ww < w; ++ww) wo += wsum[ww];
  int excl = s + wo + incl - v;
  int node = (b << 8) + t;
  if (node < N_NODES) rp[node] = excl;
  __syncthreads();
  hist[t] = excl;    // reuse as cursor
  __syncthreads();
  for (int i = s + t; i < e; i += 256) {
    unsigned u = tmp[i];
    int pos = atomicAdd(&hist[u >> 24], 1);
    cs[pos] = (int)(u & 0xFFFFFFu);
  }
  if (b == 0 && t == 0) rp[N_NODES] = N_EDGES;
}

// ---------------- feature conversion / aggregation ----------------

// x f32 -> bf16 into Acat[:,128:256]
__global__ void k_cvt_x(const float* __restrict__ x, short* __restrict__ Acat) {
  int id = blockIdx.x * 256 + threadIdx.x;
  if (id >= N_NODES * 32) return;
  int node = id >> 5, c4 = id & 31;
  float4 v = *(const float4*)(x + (size_t)node * 128 + c4 * 4);
  uint2 u;
  u.x = (unsigned)f2bf(v.x) | ((unsigned)f2bf(v.y) << 16);
  u.y = (unsigned)f2bf(v.z) | ((unsigned)f2bf(v.w) << 16);
  *(uint2*)(Acat + (size_t)node * 256 + 128 + c4 * 4) = u;
}

// Node-per-wave aggregation, dual-edge dwordx2 gathers.
// Lanes 0-31 process edge i, lanes 32-63 edge i+1; each lane loads 8B
// (4 bf16 cols). One instr = 512B = 2 edges; 16-deep batch = 32 edges /
// 8KB in flight per wave. cs reads stay scalar (contiguous per round);
// half-select is one v_cndmask. Ragged last round clamps j to last edge;
// total over-count = over*row[last], subtracted once after the
// cross-half __shfl_xor combine (exact to ~ulps).
// Gathered slice = shorts [GOFF, GOFF+128) of each 256-short source row.
// RESID: add src[t,128:256], write f32 to dst_f32; else bf16 to dst_bf.
template <bool RESID, int GOFF>
__global__ __launch_bounds__(256) void k_agg(const int* __restrict__ rp,
                                             const int* __restrict__ cs,
                                             const short* __restrict__ src,
                                             short* __restrict__ dst_bf,
                                             float* __restrict__ dst_f32) {
  const int t = __builtin_amdgcn_readfirstlane(blockIdx.x * 4 + (threadIdx.x >> 6));
  if (t >= N_NODES) return;
  const int lane = threadIdx.x & 63;
  const int half = lane >> 5;
  const int l2 = lane & 31;
  const int s = rp[t], e = rp[t + 1];
  float a0 = 0.f, a1 = 0.f, a2 = 0.f, a3 = 0.f;
  float sub0 = 0.f, sub1 = 0.f, sub2 = 0.f, sub3 = 0.f;
  const short* gb = src + GOFF + 4 * l2;
  int i = s;
  // full rounds: 32 edges, unclamped contiguous scalar cs reads
  for (; i + 32 <= e; i += 32) {
    uint2 u[16];
    #pragma unroll
    for (int q = 0; q < 16; ++q) {
      int c0 = cs[i + 2 * q];
      int c1 = cs[i + 2 * q + 1];
      int cse = half ? c1 : c0;
      u[q] = *(const uint2*)(gb + (size_t)cse * 256);
    }
    #pragma unroll
    for (int q = 0; q < 16; ++q) {
      a0 += bf2f((unsigned short)u[q].x);
      a1 += bf2f((unsigned short)(u[q].x >> 16));
      a2 += bf2f((unsigned short)u[q].y);
      a3 += bf2f((unsigned short)(u[q].y >> 16));
    }
  }
  // ragged round: clamped, still 16 loads in flight
  if (i < e) {
    const int last = e - 1;
    uint2 u[16];
    #pragma unroll
    for (int q = 0; q < 16; ++q) {
      int j0 = i + 2 * q;     j0 = (j0 < last) ? j0 : last;
      int j1 = i + 2 * q + 1; j1 = (j1 < last) ? j1 : last;
      int c0 = cs[j0];
      int c1 = cs[j1];
      int cse = half ? c1 : c0;
      u[q] = *(const uint2*)(gb + (size_t)cse * 256);
    }
    #pragma unroll
    for (int q = 0; q < 16; ++q) {
      a0 += bf2f((unsigned short)u[q].x);
      a1 += bf2f((unsigned short)(u[q].x >> 16));
      a2 += bf2f((unsigned short)u[q].y);
      a3 += bf2f((unsigned short)(u[q].y >> 16));
    }
    const int over = (i + 32) - e;     // 1..31 extra reads of row[last]
    uint2 ul = *(const uint2*)(gb + (size_t)cs[last] * 256);
    float c = (float)over;
    sub0 = c * bf2f((unsigned short)ul.x);
    sub1 = c * bf2f((unsigned short)(ul.x >> 16));
    sub2 = c * bf2f((unsigned short)ul.y);
    sub3 = c * bf2f((unsigned short)(ul.y >> 16));
  }
  // combine the two edge-halves (both halves end with the full sum)
  a0 += __shfl_xor(a0, 32);
  a1 += __shfl_xor(a1, 32);
  a2 += __shfl_xor(a2, 32);
  a3 += __shfl_xor(a3, 32);
  a0 -= sub0; a1 -= sub1; a2 -= sub2; a3 -= sub3;

  if (half == 0) {
    if (RESID) {
      uint2 r = *(const uint2*)(src + (size_t)t * 256 + 128 + 4 * l2);
      a0 += bf2f((unsigned short)r.x);
      a1 += bf2f((unsigned short)(r.x >> 16));
      a2 += bf2f((unsigned short)r.y);
      a3 += bf2f((unsigned short)(r.y >> 16));
      float4 o = {a0, a1, a2, a3};
      *(float4*)(dst_f32 + (size_t)t * 128 + 4 * l2) = o;
    } else {
      uint2 o;
      o.x = (unsigned)f2bf(a0) | ((unsigned)f2bf(a1) << 16);
      o.y = (unsigned)f2bf(a2) | ((unsigned)f2bf(a3) << 16);
      *(uint2*)(dst_bf + (size_t)t * 256 + 4 * l2) = o;
    }
  }
}

// ---------------- GEMM ----------------

// Fused pack of both weight matrices into MFMA-B fragment layout.
// id < 65536: Bp1 = vstack(Wl1, Wr1) (256x256); else Bp2 = hstack(Wl2, Wr2).
__global__ void k_packs(const float* __restrict__ Wl1, const float* __restrict__ Wr1,
                        const float* __restrict__ Wl2, const float* __restrict__ Wr2,
                        short* __restrict__ Bp1, short* __restrict__ Bp2) {
  int id = blockIdx.x * 256 + threadIdx.x;
  bool second = id >= 65536;
  int lid = id & 65535;
  int j = lid & 7;
  int lane = (lid >> 3) & 63;
  int blk = lid >> 9;
  int nb = blk & 15;
  int kk = blk >> 4;
  int k = kk * 32 + (lane >> 4) * 8 + j;
  int c = nb * 16 + (lane & 15);
  float v;
  if (!second) v = (k < 128) ? Wl1[k * 256 + c] : Wr1[(k - 128) * 256 + c];
  else         v = (c < 128) ? Wl2[k * 128 + c] : Wr2[k * 128 + (c - 128)];
  (second ? Bp2 : Bp1)[lid] = (short)f2bf(v);
}

// C[M x 256] = A[M x 256](bf16) * Bp (+bias per BIAS_MODE), optional relu.
// 128x128 tile, 4 waves 2x2, each wave 64x64 (4x4 16x16x32 frags).
// Grid dim3(2, 784); XCD-chunked bijective decode so both col-halves of a
// row-tile run consecutively on the SAME XCD -> A-tile L2 reuse.
// BIAS_MODE: 0 = bias[colg]; 1 = colg<128 ? 0 : bias[colg-128]
template <int KK, int NBTOT, bool RELU, bool OUT_BF16, int BIAS_MODE>
__global__ __launch_bounds__(256) void k_gemm(const short* __restrict__ A, int lda,
                                              const short* __restrict__ Bp,
                                              const float* __restrict__ bias,
                                              void* __restrict__ out, int ldc,
                                              int mlimit) {
  const int L = blockIdx.x + 2 * blockIdx.y;
  const int xcd = L & 7;
  const int rnd = L >> 3;          // 0..195
  const int colhalf = rnd & 1;
  const int rt = (rnd >> 1) + 98 * xcd;
  if (rt >= MTILES) return;

  const int lane = threadIdx.x & 63;
  const int wave = threadIdx.x >> 6;
  const int wr = wave >> 1, wc = wave & 1;
  const int row0 = rt * 128 + wr * 64;
  const int colbase = colhalf * 128 + wc * 64;
  const int arow = lane & 15;
  const int kgrp = lane >> 4;

  f32x4 acc[4][4];
  const f32x4 zero = {0.f, 0.f, 0.f, 0.f};
  #pragma unroll
  for (int a = 0; a < 4; ++a)
    #pragma unroll
    for (int b = 0; b < 4; ++b) acc[a][b] = zero;

  const short* Bbase = Bp + (size_t)lane * 8;
  for (int kk = 0; kk < KK; ++kk) {
    short8 af[4], bfr[4];
    const int kb = kk * 32 + kgrp * 8;
    #pragma unroll
    for (int mi = 0; mi < 4; ++mi)
      af[mi] = *(const short8*)(A + (size_t)(row0 + mi * 16 + arow) * lda + kb);
    #pragma unroll
    for (int ni = 0; ni < 4; ++ni) {
      int nb = (colbase >> 4) + ni;
      bfr[ni] = *(const short8*)(Bbase + ((size_t)(kk * NBTOT + nb) << 9));
    }
    #pragma unroll
    for (int mi = 0; mi < 4; ++mi)
      #pragma unroll
      for (int ni = 0; ni < 4; ++ni)
        acc[mi][ni] = __builtin_amdgcn_mfma_f32_16x16x32_bf16(af[mi], bfr[ni],
                                                              acc[mi][ni], 0, 0, 0);
  }

  const int ccol = lane & 15;
  const int crow = (lane >> 4) * 4;
  #pragma unroll
  for (int ni = 0; ni < 4; ++ni) {
    const int colg = colbase + ni * 16 + ccol;
    float bv;
    if (BIAS_MODE == 0) bv = bias[colg];
    else bv = (colg < 128) ? 0.f : bias[colg - 128];
    #pragma unroll
    for (int mi = 0; mi < 4; ++mi) {
      #pragma unroll
      for (int j = 0; j < 4; ++j) {
        int rowg = row0 + mi * 16 + crow + j;
        float v = acc[mi][ni][j] + bv;
        if (RELU) v = fmaxf(v, 0.0f);
        if (OUT_BF16) {
          ((short*)out)[(size_t)rowg * ldc + colg] = (short)f2bf(v);
        } else {
          if (rowg < mlimit)
            ((float*)out)[(size_t)rowg * ldc + colg] = v;
        }
      }
    }
  }
}

extern "C" void kernel_launch(void* const* d_in, const int* in_sizes, int n_in,
                              void* d_out, int out_size, void* d_ws, size_t ws_size,
                              hipStream_t stream) {
  const float* x   = (const float*)d_in[0];
  const int*   row = (const int*)d_in[1];
  const int*   col = (const int*)d_in[2];
  const float* Wl1 = (const float*)d_in[3];
  const float* bl1 = (const float*)d_in[4];
  const float* Wr1 = (const float*)d_in[5];
  const float* Wl2 = (const float*)d_in[6];
  const float* bl2 = (const float*)d_in[7];
  const float* Wr2 = (const float*)d_in[8];
  float* out = (float*)d_out;

  char* w = (char*)d_ws;
  auto alloc = [&](size_t bytes) {
    char* p = w;
    w += (bytes + 255) & ~(size_t)255;
    return p;
  };
  short* Acat = (short*)alloc((size_t)MPAD * 256 * 2);  // [agg_x_bf16 | x_bf16]
  short* Hbuf = (short*)alloc((size_t)MPAD * 256 * 2);  // h (post-relu), bf16
  short* P    = (short*)alloc((size_t)MPAD * 256 * 2);  // [h@Wl2 | h@Wr2+bl2], bf16
  short* Bp1  = (short*)alloc(65536 * 2);               // [Wl1;Wr1] packed (vcat)
  short* Bp2  = (short*)alloc(65536 * 2);               // [Wl2|Wr2] packed (hcat)
  int* rp   = (int*)alloc((N_NODES + 1) * 4);
  int* cs   = (int*)alloc((size_t)N_EDGES * 4);
  unsigned* tmp = (unsigned*)alloc((size_t)N_EDGES * 4);
  int* Hc   = (int*)alloc((size_t)NB * NBLK_A * 4);
  int* G    = (int*)alloc((size_t)NB * NBLK_A * 4);
  int* Boff = (int*)alloc((NB + 1) * 4);

  // --- CSR build: two-level counting sort (no global data atomics) ---
  k_bhist<<<NBLK_A, 256, 0, stream>>>(row, Hc);
  k_bscan<<<1, 512, 0, stream>>>(Hc, Boff);
  k_bexp<<<NB, 64, 0, stream>>>(Hc, Boff, G);
  k_bscat<<<NBLK_A, 256, 0, stream>>>(row, col, G, tmp);
  k_bsort<<<NB, 256, 0, stream>>>(tmp, Boff, rp, cs);

  // --- weight packing + x conversion (independent of CSR) ---
  k_cvt_x<<<(N_NODES * 32 + 255) / 256, 256, 0, stream>>>(x, Acat);
  k_packs<<<512, 256, 0, stream>>>(Wl1, Wr1, Wl2, Wr2, Bp1, Bp2);

  // --- layer 1: agg(x) ; h = relu([agg|x] @ [Wl1;Wr1] + bl1) -> Hbuf bf16 ---
  k_agg<false, 128><<<(N_NODES + 3) / 4, 256, 0, stream>>>(
      rp, cs, Acat, Acat, nullptr);
  k_gemm<8, 16, true, true, 0><<<dim3(2, 784), 256, 0, stream>>>(
      Acat, 256, Bp1, bl1, Hbuf, 256, MPAD);

  // --- layer 2: P = h @ [Wl2 | Wr2] (+bl2 on right half) ; out = agg(P_l) + P_r ---
  k_gemm<8, 16, false, true, 1><<<dim3(2, 784), 256, 0, stream>>>(
      Hbuf, 256, Bp2, bl2, P, 256, MPAD);
  k_agg<true, 0><<<(N_NODES + 3) / 4, 256, 0, stream>>>(
      rp, cs, P, nullptr, out);
}